// Round 3
// baseline (230.903 us; speedup 1.0000x reference)
//
#include <hip/hip_runtime.h>
#include <hip/hip_cooperative_groups.h>
#include <math.h>

namespace cg = cooperative_groups;

#define NODES 4096
#define FEATS 256
#define BATCH 1024
#define LR_C 0.5f
#define SIGMA_C 70.4f

typedef _Float16 f16x8 __attribute__((ext_vector_type(8)));
typedef float floatx4 __attribute__((ext_vector_type(4)));

__device__ __forceinline__ void get_params(int it, float& lr, float& r2, float& i2r2) {
    float decay = __expf(-(float)it * (SIGMA_C / 100000.0f));
    float radius = SIGMA_C * decay + 1e-6f;
    lr = LR_C * decay;
    r2 = radius * radius;
    i2r2 = 1.0f / (2.0f * r2);
}

// monotone float -> uint key; u64 key = (fkey << 32) | idx (ties -> smaller idx)
__device__ __forceinline__ unsigned fkey(float f) {
    unsigned u = __float_as_uint(f);
    return (u & 0x80000000u) ? ~u : (u | 0x80000000u);
}
__device__ __forceinline__ unsigned long long shfl_xor_u64(unsigned long long v, int mask) {
    unsigned lo = (unsigned)v, hi = (unsigned)(v >> 32);
    lo = __shfl_xor(lo, mask, 64);
    hi = __shfl_xor(hi, mask, 64);
    return ((unsigned long long)hi << 32) | lo;
}

struct SmemP0 { _Float16 T[64][72]; };
struct SmemP1 {
    _Float16 Ah[64][40], Al[64][40], Bh[64][40], Bl[64][40];
    unsigned long long rowmin[64][2];
};
struct SmemP2 {
    _Float16 As[32][136];
    _Float16 Bs[64][136];
    int bmu[1024];
    float Svl[32];
};

// One cooperative kernel, 512 blocks x 256 threads, 3 phases with grid syncs.
__global__ __launch_bounds__(256, 2) void k_som_fused(
    const float* __restrict__ X, const float* __restrict__ Wm, const int* __restrict__ itp,
    float* __restrict__ out0, float* __restrict__ out1,
    float* __restrict__ w2,
    _Float16* __restrict__ Xhi, _Float16* __restrict__ Xlo, _Float16* __restrict__ XT,
    _Float16* __restrict__ Whi, _Float16* __restrict__ Wlo,
    unsigned long long* __restrict__ gmin) {
    __shared__ union { SmemP0 p0; SmemP1 p1; SmemP2 p2; } sm;
    cg::grid_group grid = cg::this_grid();

    const int t = threadIdx.x;
    const int blk = blockIdx.x;
    const int wave = t >> 6, lane = t & 63;
    const int wm = wave & 1, wn = wave >> 1;
    const int lm = lane & 15, quad = lane >> 4;

    // ================= Phase 0: prep =================
    // W -> fp16 hi/lo + w2 (all 512 blocks); X -> fp16 hi/lo b-major + hi d-major
    // (blocks 0..63); gmin init (blocks 0..3).
#pragma unroll
    for (int rr = 0; rr < 2; ++rr) {
        int row = blk * 8 + wave * 2 + rr;
        float4 v = *(const float4*)&Wm[(size_t)row * FEATS + lane * 4];
        union { _Float16 h[4]; float2 f2; } uh, ul;
        uh.h[0] = (_Float16)v.x; uh.h[1] = (_Float16)v.y;
        uh.h[2] = (_Float16)v.z; uh.h[3] = (_Float16)v.w;
        ul.h[0] = (_Float16)(v.x - (float)uh.h[0]);
        ul.h[1] = (_Float16)(v.y - (float)uh.h[1]);
        ul.h[2] = (_Float16)(v.z - (float)uh.h[2]);
        ul.h[3] = (_Float16)(v.w - (float)uh.h[3]);
        *(float2*)&Whi[(size_t)row * FEATS + lane * 4] = uh.f2;
        *(float2*)&Wlo[(size_t)row * FEATS + lane * 4] = ul.f2;
        float s = v.x * v.x + v.y * v.y + v.z * v.z + v.w * v.w;
#pragma unroll
        for (int off = 32; off > 0; off >>= 1) s += __shfl_down(s, off, 64);
        if (lane == 0) w2[row] = s;
    }
    if (blk < 4) gmin[blk * 256 + t] = 0xFFFFFFFFFFFFFFFFULL;
    if (blk < 64) {
        const int b0 = (blk & 15) * 64, d0 = (blk >> 4) * 64;
        {
            const int bl = t >> 2, dq = (t & 3) * 16;
            union { _Float16 h[16]; float4 q[2]; } uh, ul;
#pragma unroll
            for (int c = 0; c < 4; ++c) {
                float4 v = *(const float4*)&X[(size_t)(b0 + bl) * FEATS + d0 + dq + c * 4];
                uh.h[c * 4 + 0] = (_Float16)v.x; uh.h[c * 4 + 1] = (_Float16)v.y;
                uh.h[c * 4 + 2] = (_Float16)v.z; uh.h[c * 4 + 3] = (_Float16)v.w;
                ul.h[c * 4 + 0] = (_Float16)(v.x - (float)uh.h[c * 4 + 0]);
                ul.h[c * 4 + 1] = (_Float16)(v.y - (float)uh.h[c * 4 + 1]);
                ul.h[c * 4 + 2] = (_Float16)(v.z - (float)uh.h[c * 4 + 2]);
                ul.h[c * 4 + 3] = (_Float16)(v.w - (float)uh.h[c * 4 + 3]);
            }
            *(float4*)&Xhi[(size_t)(b0 + bl) * FEATS + d0 + dq] = uh.q[0];
            *(float4*)&Xhi[(size_t)(b0 + bl) * FEATS + d0 + dq + 8] = uh.q[1];
            *(float4*)&Xlo[(size_t)(b0 + bl) * FEATS + d0 + dq] = ul.q[0];
            *(float4*)&Xlo[(size_t)(b0 + bl) * FEATS + d0 + dq + 8] = ul.q[1];
#pragma unroll
            for (int c = 0; c < 16; ++c) sm.p0.T[bl][dq + c] = uh.h[c];
        }
        __syncthreads();
        {
            const int dl = t >> 2, bq = (t & 3) * 16;
            union { _Float16 h[16]; float4 q[2]; } u;
#pragma unroll
            for (int c = 0; c < 16; ++c) u.h[c] = sm.p0.T[bq + c][dl];
            *(float4*)&XT[(size_t)(d0 + dl) * BATCH + b0 + bq] = u.q[0];
            *(float4*)&XT[(size_t)(d0 + dl) * BATCH + b0 + bq + 8] = u.q[1];
        }
    }

    grid.sync();

    // ================= Phase 1: gemm1 + rowmin =================
    // 1024 (n0,b0) tiles over 512 blocks: 2 b-halves per block.
    {
        const int nt = blk >> 3;  // 0..63
        const int n0 = nt * 64;
        const int srow = t >> 2, skoff = (t & 3) * 8;
        for (int half = 0; half < 2; ++half) {
            const int b0 = (((blk & 7) << 1) | half) * 64;
            floatx4 acc[2][2] = {};
            for (int k0 = 0; k0 < FEATS; k0 += 32) {
                *(float4*)&sm.p1.Ah[srow][skoff] = *(const float4*)&Xhi[(size_t)(b0 + srow) * FEATS + k0 + skoff];
                *(float4*)&sm.p1.Al[srow][skoff] = *(const float4*)&Xlo[(size_t)(b0 + srow) * FEATS + k0 + skoff];
                *(float4*)&sm.p1.Bh[srow][skoff] = *(const float4*)&Whi[(size_t)(n0 + srow) * FEATS + k0 + skoff];
                *(float4*)&sm.p1.Bl[srow][skoff] = *(const float4*)&Wlo[(size_t)(n0 + srow) * FEATS + k0 + skoff];
                __syncthreads();
                f16x8 ah[2], al[2], bh[2], bl[2];
                ah[0] = *(f16x8*)&sm.p1.Ah[wm * 32 + lm][quad * 8];
                ah[1] = *(f16x8*)&sm.p1.Ah[wm * 32 + 16 + lm][quad * 8];
                al[0] = *(f16x8*)&sm.p1.Al[wm * 32 + lm][quad * 8];
                al[1] = *(f16x8*)&sm.p1.Al[wm * 32 + 16 + lm][quad * 8];
                bh[0] = *(f16x8*)&sm.p1.Bh[wn * 32 + lm][quad * 8];
                bh[1] = *(f16x8*)&sm.p1.Bh[wn * 32 + 16 + lm][quad * 8];
                bl[0] = *(f16x8*)&sm.p1.Bl[wn * 32 + lm][quad * 8];
                bl[1] = *(f16x8*)&sm.p1.Bl[wn * 32 + 16 + lm][quad * 8];
#pragma unroll
                for (int i = 0; i < 2; ++i)
#pragma unroll
                    for (int j = 0; j < 2; ++j) {
                        acc[i][j] = __builtin_amdgcn_mfma_f32_16x16x32_f16(ah[i], bh[j], acc[i][j], 0, 0, 0);
                        acc[i][j] = __builtin_amdgcn_mfma_f32_16x16x32_f16(ah[i], bl[j], acc[i][j], 0, 0, 0);
                        acc[i][j] = __builtin_amdgcn_mfma_f32_16x16x32_f16(al[i], bh[j], acc[i][j], 0, 0, 0);
                    }
                __syncthreads();
            }
            const int col0 = n0 + wn * 32 + lm, col1 = col0 + 16;
            const float w20 = w2[col0], w21 = w2[col1];
#pragma unroll
            for (int i = 0; i < 2; ++i) {
#pragma unroll
                for (int r = 0; r < 4; ++r) {
                    float va = w20 - 2.0f * acc[i][0][r];
                    float vb = w21 - 2.0f * acc[i][1][r];
                    unsigned long long ka = ((unsigned long long)fkey(va) << 32) | (unsigned)col0;
                    unsigned long long kb = ((unsigned long long)fkey(vb) << 32) | (unsigned)col1;
                    unsigned long long m = ka < kb ? ka : kb;
#pragma unroll
                    for (int mk = 1; mk < 16; mk <<= 1) {
                        unsigned long long o = shfl_xor_u64(m, mk);
                        if (o < m) m = o;
                    }
                    if (lm == 0) sm.p1.rowmin[wm * 32 + i * 16 + quad * 4 + r][wn] = m;
                }
            }
            __syncthreads();
            if (t < 64) {
                unsigned long long v = sm.p1.rowmin[t][0];
                if (sm.p1.rowmin[t][1] < v) v = sm.p1.rowmin[t][1];
                atomicMin(&gmin[b0 + t], v);
            }
            __syncthreads();
        }
    }

    grid.sync();

    // ================= Phase 2: fused gemm2 =================
    // 512 tiles, 1:1 with blocks. d0 = (blk&3)*64, n0 = (blk>>2)*32.
    {
        const int d0 = (blk & 3) * 64;
        const int n0 = (blk >> 2) * 32;

#pragma unroll
        for (int j = 0; j < 4; ++j)
            sm.p2.bmu[t + j * 256] = (int)(gmin[t + j * 256] & 0xFFFFFFFFULL);
        float lr, r2, i2r2;
        get_params(itp[0], lr, r2, i2r2);
        if ((blk & 3) == 0 && (blk >> 2) < 4)
            out1[(blk >> 2) * 256 + t] = (float)(int)(gmin[(blk >> 2) * 256 + t] & 0xFFFFFFFFULL);
        __syncthreads();

        // A-gen geometry: 32 rows x 128 cols per K-step, 16 cols/thread
        const int arow = t >> 3, ac = (t & 7) * 16;
        const int nn = n0 + arow;
        const int ni = nn >> 6, nj = nn & 63;
        // B staging geometry
        const int brow = t >> 2, bcoff = (t & 3) * 32;

        float ssum = 0.0f;
        floatx4 acc0 = {}, acc1 = {};
        for (int k0 = 0; k0 < BATCH; k0 += 128) {
            union { _Float16 h[16]; float4 q[2]; } u;
#pragma unroll
            for (int c = 0; c < 16; ++c) {
                int m = sm.p2.bmu[k0 + ac + c];
                int di = ni - (m >> 6); di = di < 0 ? -di : di;
                int dj = nj - (m & 63); dj = dj < 0 ? -dj : dj;
                float d2f = (float)(di * di + dj * dj);
                float val = (d2f <= r2) ? lr * __expf(-d2f * i2r2) : 0.0f;
                u.h[c] = (_Float16)val;
                ssum += val;
            }
            *(float4*)&sm.p2.As[arow][ac] = u.q[0];
            *(float4*)&sm.p2.As[arow][ac + 8] = u.q[1];
#pragma unroll
            for (int c = 0; c < 4; ++c)
                *(float4*)&sm.p2.Bs[brow][bcoff + c * 8] =
                    *(const float4*)&XT[(size_t)(d0 + brow) * BATCH + k0 + bcoff + c * 8];
            __syncthreads();
#pragma unroll
            for (int ks = 0; ks < 128; ks += 32) {
                f16x8 a = *(f16x8*)&sm.p2.As[wm * 16 + lm][ks + quad * 8];
                f16x8 b0 = *(f16x8*)&sm.p2.Bs[wn * 32 + lm][ks + quad * 8];
                f16x8 b1 = *(f16x8*)&sm.p2.Bs[wn * 32 + 16 + lm][ks + quad * 8];
                acc0 = __builtin_amdgcn_mfma_f32_16x16x32_f16(a, b0, acc0, 0, 0, 0);
                acc1 = __builtin_amdgcn_mfma_f32_16x16x32_f16(a, b1, acc1, 0, 0, 0);
            }
            __syncthreads();
        }
#pragma unroll
        for (int mk = 1; mk < 8; mk <<= 1) ssum += __shfl_xor(ssum, mk, 64);
        if ((t & 7) == 0) sm.p2.Svl[arow] = ssum;
        __syncthreads();

        const float invB = 1.0f / (float)BATCH;
#pragma unroll
        for (int r = 0; r < 4; ++r) {
            int rowN = n0 + wm * 16 + quad * 4 + r;
            float cc = 1.0f - sm.p2.Svl[rowN - n0] * invB;
            int col0 = d0 + wn * 32 + lm;
            int col1 = col0 + 16;
            out0[(size_t)rowN * FEATS + col0] = Wm[(size_t)rowN * FEATS + col0] * cc + acc0[r] * invB;
            out0[(size_t)rowN * FEATS + col1] = Wm[(size_t)rowN * FEATS + col1] * cc + acc1[r] * invB;
        }
    }
}

extern "C" void kernel_launch(void* const* d_in, const int* in_sizes, int n_in,
                              void* d_out, int out_size, void* d_ws, size_t ws_size,
                              hipStream_t stream) {
    const float* X = (const float*)d_in[0];    // (1024, 256)
    const float* Wm = (const float*)d_in[1];   // (4096, 256)
    const int* itp = (const int*)d_in[2];      // scalar iteration
    float* out0 = (float*)d_out;
    float* out1 = out0 + (size_t)NODES * FEATS;

    char* ws = (char*)d_ws;
    float* w2       = (float*)(ws + 0);              // 16 KB
    _Float16* Xhi   = (_Float16*)(ws + 16384);       // 512 KB
    _Float16* Xlo   = (_Float16*)(ws + 540672);      // 512 KB
    _Float16* XT    = (_Float16*)(ws + 1064960);     // 512 KB
    _Float16* Whi   = (_Float16*)(ws + 1589248);     // 2 MB
    _Float16* Wlo   = (_Float16*)(ws + 3686400);     // 2 MB
    unsigned long long* gmin = (unsigned long long*)(ws + 5783552);  // 8 KB

    void* args[] = {(void*)&X, (void*)&Wm, (void*)&itp, (void*)&out0, (void*)&out1,
                    (void*)&w2, (void*)&Xhi, (void*)&Xlo, (void*)&XT,
                    (void*)&Whi, (void*)&Wlo, (void*)&gmin};
    hipLaunchCooperativeKernel((const void*)k_som_fused, dim3(512), dim3(256), args, 0, stream);
}

// Round 4
// 89.807 us; speedup vs baseline: 2.5711x; 2.5711x over previous
//
#include <hip/hip_runtime.h>
#include <math.h>

#define NODES 4096
#define FEATS 256
#define BATCH 1024
#define LR_C 0.5f
#define SIGMA_C 70.4f

typedef _Float16 f16x8 __attribute__((ext_vector_type(8)));
typedef float floatx4 __attribute__((ext_vector_type(4)));

__device__ __forceinline__ void get_params(int it, float& lr, float& r2, float& i2r2) {
    float decay = __expf(-(float)it * (SIGMA_C / 100000.0f));
    float radius = SIGMA_C * decay + 1e-6f;
    lr = LR_C * decay;
    r2 = radius * radius;
    i2r2 = 1.0f / (2.0f * r2);
}

// monotone float -> uint key; u64 key = (fkey << 32) | idx (ties -> smaller idx)
__device__ __forceinline__ unsigned fkey(float f) {
    unsigned u = __float_as_uint(f);
    return (u & 0x80000000u) ? ~u : (u | 0x80000000u);
}
__device__ __forceinline__ unsigned long long shfl_xor_u64(unsigned long long v, int mask) {
    unsigned lo = (unsigned)v, hi = (unsigned)(v >> 32);
    lo = __shfl_xor(lo, mask, 64);
    hi = __shfl_xor(hi, mask, 64);
    return ((unsigned long long)hi << 32) | lo;
}

// ---- K1: gemm1+min with INLINE fp32->fp16-split conversion (no prep kernel).
//      sqd via xh*wh + xh*wl + xl*wh MFMA; w2 computed in-block from staged fp32;
//      XT (X^T fp16-hi, d-major) emitted from Ah tiles by blocks x==k0>>5;
//      per-row packed-u64 atomicMin -> gmin (pre-initialized to 0xFF via memset).
__global__ __launch_bounds__(256) void k_gemm1min(const float* __restrict__ X, const float* __restrict__ Wm,
                                                  _Float16* __restrict__ XT,
                                                  unsigned long long* __restrict__ gmin) {
    __shared__ _Float16 Ah[64][40];
    __shared__ _Float16 Al[64][40];
    __shared__ _Float16 Bh[64][40];
    __shared__ _Float16 Bl[64][40];
    __shared__ unsigned long long rowmin[64][2];
    __shared__ float w2s[64][4];
    const int n0 = blockIdx.x * 64;
    const int b0 = blockIdx.y * 64;
    const int t = threadIdx.x;
    const int wave = t >> 6, lane = t & 63;
    const int wm = wave & 1, wn = wave >> 1;
    const int lm = lane & 15, quad = lane >> 4;
    const int srow = t >> 2, skoff = (t & 3) * 8;
    float wsq = 0.0f;
    floatx4 acc[2][2] = {};
    for (int k0 = 0; k0 < FEATS; k0 += 32) {
        // load fp32 sources (8 floats each for A-row and B-row chunk)
        float xa[8], wa[8];
        *(float4*)&xa[0] = *(const float4*)&X[(size_t)(b0 + srow) * FEATS + k0 + skoff];
        *(float4*)&xa[4] = *(const float4*)&X[(size_t)(b0 + srow) * FEATS + k0 + skoff + 4];
        *(float4*)&wa[0] = *(const float4*)&Wm[(size_t)(n0 + srow) * FEATS + k0 + skoff];
        *(float4*)&wa[4] = *(const float4*)&Wm[(size_t)(n0 + srow) * FEATS + k0 + skoff + 4];
        union { _Float16 h[8]; float4 q; } xh, xl, wh, wl;
#pragma unroll
        for (int i = 0; i < 8; ++i) {
            xh.h[i] = (_Float16)xa[i];
            xl.h[i] = (_Float16)(xa[i] - (float)xh.h[i]);
            wh.h[i] = (_Float16)wa[i];
            wl.h[i] = (_Float16)(wa[i] - (float)wh.h[i]);
            wsq += wa[i] * wa[i];
        }
        *(float4*)&Ah[srow][skoff] = xh.q;
        *(float4*)&Al[srow][skoff] = xl.q;
        *(float4*)&Bh[srow][skoff] = wh.q;
        *(float4*)&Bl[srow][skoff] = wl.q;
        __syncthreads();
        f16x8 ah[2], al[2], bh[2], bl[2];
        ah[0] = *(f16x8*)&Ah[wm * 32 + lm][quad * 8];
        ah[1] = *(f16x8*)&Ah[wm * 32 + 16 + lm][quad * 8];
        al[0] = *(f16x8*)&Al[wm * 32 + lm][quad * 8];
        al[1] = *(f16x8*)&Al[wm * 32 + 16 + lm][quad * 8];
        bh[0] = *(f16x8*)&Bh[wn * 32 + lm][quad * 8];
        bh[1] = *(f16x8*)&Bh[wn * 32 + 16 + lm][quad * 8];
        bl[0] = *(f16x8*)&Bl[wn * 32 + lm][quad * 8];
        bl[1] = *(f16x8*)&Bl[wn * 32 + 16 + lm][quad * 8];
#pragma unroll
        for (int i = 0; i < 2; ++i)
#pragma unroll
            for (int j = 0; j < 2; ++j) {
                acc[i][j] = __builtin_amdgcn_mfma_f32_16x16x32_f16(ah[i], bh[j], acc[i][j], 0, 0, 0);
                acc[i][j] = __builtin_amdgcn_mfma_f32_16x16x32_f16(ah[i], bl[j], acc[i][j], 0, 0, 0);
                acc[i][j] = __builtin_amdgcn_mfma_f32_16x16x32_f16(al[i], bh[j], acc[i][j], 0, 0, 0);
            }
        // XT emission: blocks x == k0>>5 write X^T-hi for this (b-slice, k-chunk).
        // Reads Ah (stable between barriers); 128B-contiguous global stores.
        if (blockIdx.x == (k0 >> 5)) {
            const int dcol = t >> 3, bch = (t & 7) * 8;
            union { _Float16 h[8]; float4 q; } u;
#pragma unroll
            for (int j = 0; j < 8; ++j) u.h[j] = Ah[bch + j][dcol];
            *(float4*)&XT[(size_t)(k0 + dcol) * BATCH + b0 + bch] = u.q;
        }
        __syncthreads();
    }
    // w2 from per-thread partials (4 chunks per row)
    w2s[srow][t & 3] = wsq;
    __syncthreads();
    const int col0 = n0 + wn * 32 + lm, col1 = col0 + 16;
    const int r0 = wn * 32 + lm, r1 = r0 + 16;
    const float w20 = w2s[r0][0] + w2s[r0][1] + w2s[r0][2] + w2s[r0][3];
    const float w21 = w2s[r1][0] + w2s[r1][1] + w2s[r1][2] + w2s[r1][3];
#pragma unroll
    for (int i = 0; i < 2; ++i) {
#pragma unroll
        for (int r = 0; r < 4; ++r) {
            float va = w20 - 2.0f * acc[i][0][r];
            float vb = w21 - 2.0f * acc[i][1][r];
            unsigned long long ka = ((unsigned long long)fkey(va) << 32) | (unsigned)col0;
            unsigned long long kb = ((unsigned long long)fkey(vb) << 32) | (unsigned)col1;
            unsigned long long m = ka < kb ? ka : kb;
#pragma unroll
            for (int mk = 1; mk < 16; mk <<= 1) {
                unsigned long long o = shfl_xor_u64(m, mk);
                if (o < m) m = o;
            }
            if (lm == 0) rowmin[wm * 32 + i * 16 + quad * 4 + r][wn] = m;
        }
    }
    __syncthreads();
    if (t < 64) {
        unsigned long long v = rowmin[t][0];
        if (rowmin[t][1] < v) v = rowmin[t][1];
        atomicMin(&gmin[b0 + t], v);
    }
}

// ---- K2 (fused): gemm2 with on-the-fly A-tile generation from gmin.
//      A[n][b] = lr_op^T computed in-kernel, per-block row-sum replaces Svec,
//      out1 written by d0==0 blocks. Epilogue: out0 = Wm*(1 - rowsum/B) + acc/B.
__global__ __launch_bounds__(256) void k_gemm2f(const _Float16* __restrict__ XT,
                                                const unsigned long long* __restrict__ gmin,
                                                const int* __restrict__ itp,
                                                const float* __restrict__ Wm,
                                                float* __restrict__ out0, float* __restrict__ out1) {
    __shared__ _Float16 As[32][136];
    __shared__ _Float16 Bs[64][136];
    __shared__ int bmu_s[1024];
    __shared__ float Svl[32];
    const int d0 = blockIdx.x * 64;
    const int n0 = blockIdx.y * 32;
    const int t = threadIdx.x;
    const int wave = t >> 6, lane = t & 63;
    const int wm = wave & 1, wn = wave >> 1;
    const int lm = lane & 15, quad = lane >> 4;

#pragma unroll
    for (int j = 0; j < 4; ++j)
        bmu_s[t + j * 256] = (int)(gmin[t + j * 256] & 0xFFFFFFFFULL);
    float lr, r2, i2r2;
    get_params(itp[0], lr, r2, i2r2);
    if (blockIdx.x == 0 && blockIdx.y < 4)
        out1[blockIdx.y * 256 + t] = (float)(int)(gmin[blockIdx.y * 256 + t] & 0xFFFFFFFFULL);
    __syncthreads();

    // A-gen geometry: 32 rows x 128 cols per K-step, 16 cols/thread
    const int arow = t >> 3, ac = (t & 7) * 16;
    const int nn = n0 + arow;
    const int ni = nn >> 6, nj = nn & 63;
    // B staging geometry
    const int brow = t >> 2, bcoff = (t & 3) * 32;

    float ssum = 0.0f;
    floatx4 acc0 = {}, acc1 = {};
    for (int k0 = 0; k0 < BATCH; k0 += 128) {
        union { _Float16 h[16]; float4 q[2]; } u;
#pragma unroll
        for (int c = 0; c < 16; ++c) {
            int m = bmu_s[k0 + ac + c];
            int di = ni - (m >> 6); di = di < 0 ? -di : di;
            int dj = nj - (m & 63); dj = dj < 0 ? -dj : dj;
            float d2f = (float)(di * di + dj * dj);
            float val = (d2f <= r2) ? lr * __expf(-d2f * i2r2) : 0.0f;
            u.h[c] = (_Float16)val;
            ssum += val;
        }
        *(float4*)&As[arow][ac] = u.q[0];
        *(float4*)&As[arow][ac + 8] = u.q[1];
#pragma unroll
        for (int c = 0; c < 4; ++c)
            *(float4*)&Bs[brow][bcoff + c * 8] =
                *(const float4*)&XT[(size_t)(d0 + brow) * BATCH + k0 + bcoff + c * 8];
        __syncthreads();
#pragma unroll
        for (int ks = 0; ks < 128; ks += 32) {
            f16x8 a = *(f16x8*)&As[wm * 16 + lm][ks + quad * 8];
            f16x8 b0 = *(f16x8*)&Bs[wn * 32 + lm][ks + quad * 8];
            f16x8 b1 = *(f16x8*)&Bs[wn * 32 + 16 + lm][ks + quad * 8];
            acc0 = __builtin_amdgcn_mfma_f32_16x16x32_f16(a, b0, acc0, 0, 0, 0);
            acc1 = __builtin_amdgcn_mfma_f32_16x16x32_f16(a, b1, acc1, 0, 0, 0);
        }
        __syncthreads();
    }
#pragma unroll
    for (int mk = 1; mk < 8; mk <<= 1) ssum += __shfl_xor(ssum, mk, 64);
    if ((t & 7) == 0) Svl[arow] = ssum;
    __syncthreads();

    const float invB = 1.0f / (float)BATCH;
#pragma unroll
    for (int r = 0; r < 4; ++r) {
        int rowN = n0 + wm * 16 + quad * 4 + r;
        float cc = 1.0f - Svl[rowN - n0] * invB;
        int col0 = d0 + wn * 32 + lm;
        int col1 = col0 + 16;
        out0[(size_t)rowN * FEATS + col0] = Wm[(size_t)rowN * FEATS + col0] * cc + acc0[r] * invB;
        out0[(size_t)rowN * FEATS + col1] = Wm[(size_t)rowN * FEATS + col1] * cc + acc1[r] * invB;
    }
}

extern "C" void kernel_launch(void* const* d_in, const int* in_sizes, int n_in,
                              void* d_out, int out_size, void* d_ws, size_t ws_size,
                              hipStream_t stream) {
    const float* X = (const float*)d_in[0];    // (1024, 256)
    const float* Wm = (const float*)d_in[1];   // (4096, 256)
    const int* itp = (const int*)d_in[2];      // scalar iteration
    float* out0 = (float*)d_out;
    float* out1 = out0 + (size_t)NODES * FEATS;

    char* ws = (char*)d_ws;
    _Float16* XT = (_Float16*)(ws + 0);                              // 512 KB
    unsigned long long* gmin = (unsigned long long*)(ws + 524288);   // 8 KB

    hipMemsetAsync(gmin, 0xFF, 1024 * sizeof(unsigned long long), stream);
    k_gemm1min<<<dim3(64, 16), 256, 0, stream>>>(X, Wm, XT, gmin);
    k_gemm2f<<<dim3(4, 128), 256, 0, stream>>>(XT, gmin, itp, Wm, out0, out1);
}